// Round 10
// baseline (2853.659 us; speedup 1.0000x reference)
//
#include <hip/hip_runtime.h>
#include <hip/hip_bf16.h>

#define NB   8
#define SS   2048
#define DD   1024
#define DFFN 4096
#define MTOT (NB*SS)   // 16384

typedef unsigned short u16;
typedef __attribute__((ext_vector_type(4))) float f32x4;
typedef __attribute__((ext_vector_type(8))) short bf16x8;
typedef __attribute__((ext_vector_type(4))) int i32x4;
typedef __attribute__((ext_vector_type(4))) unsigned short u16x4;
typedef __attribute__((ext_vector_type(8))) unsigned short u16x8;

__device__ __forceinline__ u16 f2bf(float f) {
  union { float f; unsigned u; } c; c.f = f;
  unsigned r = c.u + 0x7FFFu + ((c.u >> 16) & 1u);
  return (u16)(r >> 16);
}

__device__ __forceinline__ void gload16(const void* g, void* l) {
  __builtin_amdgcn_global_load_lds(
      (const __attribute__((address_space(1))) void*)(unsigned long long)g,
      (__attribute__((address_space(3))) void*)(unsigned)(unsigned long long)l,
      16, 0, 0);
}

// opaque ds_read_b128 (manual lgkmcnt/vmcnt accounting)
__device__ __forceinline__ bf16x8 dsr128(unsigned addr) {
  i32x4 r;
  asm volatile("ds_read_b128 %0, %1" : "=v"(r) : "v"(addr));
  return __builtin_bit_cast(bf16x8, r);
}

// ---------------------------------------------------------------------------
// R5-proven 128x128 GEMM-BT: 4 waves (2x2), per-wave 64x64, BK=32, 2-buffer
// LDS ring. 32KB LDS + <=102 VGPR -> __launch_bounds__(256,5): 5 blocks/CU
// (160KB LDS exactly), 20 waves/CU of independent-block latency hiding.
// Swizzled staging (conflict-free b128), LDS-staged epilogue (full lines).
// OUTMODE: 0=bf16, 1=f32, 2=f16, 3=QKV fused (Q,K bf16 rows + V transposed).
// ---------------------------------------------------------------------------
template<int EBIAS, int EGELU, int ESCALE, int EROWSCALE, int OUTMODE, int CSKIP, int CK>
__global__ __launch_bounds__(256, 5)
void gemm128(const u16* __restrict__ A, const u16* __restrict__ B,
             const float* __restrict__ bias0, const float* __restrict__ bias1,
             const float* __restrict__ bias2, const float* __restrict__ rowscale,
             void* __restrict__ C0, void* __restrict__ C1, void* __restrict__ C2,
             int K, int lda, int ldb, int ldc, float scale,
             long long sA, long long sB, long long sC, int sRS)
{
  __shared__ __align__(1024) u16 smem[16384];   // 32 KB

  const int nwg = gridDim.x * gridDim.y;
  const int orig = blockIdx.y * gridDim.x + blockIdx.x;
  const int q = nwg >> 3, r = nwg & 7;
  const int xcd = orig & 7, pos0 = orig >> 3;
  const int wg = (xcd < r ? xcd * (q + 1) : r * (q + 1) + (xcd - r) * q) + pos0;
  const int bx = wg % gridDim.x, by = wg / gridDim.x;
  const int row0 = by * 128, col0 = bx * 128;
  if (CSKIP && col0 > row0 + 127) return;

  const int z = blockIdx.z;
  A += (size_t)z * sA;
  B += (size_t)z * sB;

  int nkt = K >> 5;
  if (CK) { int lim = (row0 + 128) >> 5; if (lim < nkt) nkt = lim; }

  const int tid  = threadIdx.x;
  const int wid  = tid >> 6;
  const int lane = tid & 63;
  const int wr = wid >> 1, wc = wid & 1;

  const int srow = wid * 16 + (lane >> 2);
  const int sunit = (lane & 3) ^ ((lane >> 3) & 3);
  const char* gA = (const char*)A + ((size_t)(row0 + srow) * lda + sunit * 8) * 2;
  const char* gB = (const char*)B + ((size_t)(col0 + srow) * ldb + sunit * 8) * 2;
  const size_t ldab = (size_t)64 * lda * 2;
  const size_t ldbb = (size_t)64 * ldb * 2;

  #define STG(t2) { char* lb = (char*)smem + ((t2) & 1) * 16384; size_t kb = (size_t)(t2) * 64; \
      gload16(gA + kb,        lb + wid * 1024);                                                 \
      gload16(gA + kb + ldab, lb + 4096 + wid * 1024);                                          \
      gload16(gB + kb,        lb + 8192 + wid * 1024);                                          \
      gload16(gB + kb + ldbb, lb + 8192 + 4096 + wid * 1024); }

  const int fr = lane & 15;
  const int ks16 = ((lane >> 4) & 3) * 16;
  const int xm = ((lane >> 1) & 3) << 4;
  const unsigned sbase = (unsigned)(unsigned long long)(void*)smem;

  f32x4 acc[4][4] = {};

  STG(0);
  asm volatile("s_waitcnt vmcnt(0)");
  asm volatile("s_barrier" ::: "memory");

  for (int t = 0; t < nkt; ++t) {
    if (t + 1 < nkt) STG(t + 1);
    const unsigned cb = sbase + (t & 1) * 16384;
    bf16x8 af[4], bf[4];
#pragma unroll
    for (int m = 0; m < 4; ++m)
      af[m] = dsr128(cb + (((wr * 64 + m * 16 + fr) * 64 + ks16) ^ xm));
#pragma unroll
    for (int n = 0; n < 4; ++n)
      bf[n] = dsr128(cb + ((8192 + (wc * 64 + n * 16 + fr) * 64 + ks16) ^ xm));
    asm volatile("s_waitcnt lgkmcnt(0)");
    __builtin_amdgcn_sched_barrier(0);
    __builtin_amdgcn_s_setprio(1);
#pragma unroll
    for (int m = 0; m < 4; ++m)
#pragma unroll
      for (int n = 0; n < 4; ++n)
        acc[m][n] = __builtin_amdgcn_mfma_f32_16x16x32_bf16(af[m], bf[n], acc[m][n], 0, 0, 0);
    __builtin_amdgcn_s_setprio(0);
    asm volatile("s_waitcnt vmcnt(0)");
    asm volatile("s_barrier" ::: "memory");
  }
  #undef STG

  // ---- epilogue via LDS ----
  char* sm = (char*)smem;
  const int r4 = (lane >> 4) * 4;
  const int sel  = (OUTMODE == 3) ? (col0 >> 10) : 0;
  const int oc0  = (OUTMODE == 3) ? (col0 & 1023) : col0;
  const float* bias = (OUTMODE == 3) ? (sel == 0 ? bias0 : sel == 1 ? bias1 : bias2)
                                     : bias0;

  if (OUTMODE == 1) {
#pragma unroll
    for (int p = 0; p < 2; ++p) {
      if (wc == p) {
#pragma unroll
        for (int n = 0; n < 4; ++n) {
          const int col = oc0 + wc * 64 + n * 16 + fr;
          const int pb = (n * 16 + fr) * 4;
          float bia = EBIAS ? bias[col] : 0.0f;
#pragma unroll
          for (int m = 0; m < 4; ++m) {
#pragma unroll
            for (int j = 0; j < 4; ++j) {
              const int line = wr * 64 + m * 16 + r4 + j;
              float xv = acc[m][n][j];
              if (EBIAS)     xv += bia;
              if (ESCALE)    xv *= scale;
              if (EROWSCALE) xv *= rowscale[z * sRS + row0 + line];
              if (EGELU)     xv = 0.5f * xv * (1.0f + erff(xv * 0.70710678118f));
              *(float*)(sm + ((line * 256 + pb) ^ ((line & 7) << 4))) = xv;
            }
          }
        }
      }
      __syncthreads();
      float* Cb = (float*)C0 + (size_t)z * sC;
#pragma unroll
      for (int i = 0; i < 8; ++i) {
        const int o = i * 4096 + tid * 16;
        const int line = o >> 8, ps = o & 255;
        f32x4 v = *(const f32x4*)(sm + ((line * 256 + ps) ^ ((line & 7) << 4)));
        *(f32x4*)((char*)(Cb + (size_t)(row0 + line) * ldc + oc0 + p * 64) + ps) = v;
      }
      __syncthreads();
    }
  } else if (OUTMODE == 3 && sel == 2) {
    // V transposed: line = local col, pos = local row * 2
#pragma unroll
    for (int n = 0; n < 4; ++n) {
      const int line = wc * 64 + n * 16 + fr;
      float bia = EBIAS ? bias[oc0 + line] : 0.0f;
#pragma unroll
      for (int m = 0; m < 4; ++m) {
        const int rb = wr * 64 + m * 16 + r4;
        u16x4 pk;
#pragma unroll
        for (int j = 0; j < 4; ++j) pk[j] = f2bf(acc[m][n][j] + bia);
        *(u16x4*)(sm + ((line * 256 + rb * 2) ^ ((line & 7) << 4))) = pk;
      }
    }
    __syncthreads();
    u16* Cb = (u16*)C2 + (size_t)(row0 >> 11) * (DD * SS) + (row0 & (SS - 1));
#pragma unroll
    for (int i = 0; i < 8; ++i) {
      const int o = i * 4096 + tid * 16;
      const int line = o >> 8, ps = o & 255;
      f32x4 v = *(const f32x4*)(sm + ((line * 256 + ps) ^ ((line & 7) << 4)));
      *(f32x4*)((char*)(Cb + (size_t)(oc0 + line) * SS) + ps) = v;
    }
  } else {
    // 2-byte out (bf16 / f16 / QKV sel<2)
#pragma unroll
    for (int n = 0; n < 4; ++n) {
      const int col = oc0 + wc * 64 + n * 16 + fr;
      const int pc = (wc * 64 + n * 16 + fr) * 2;
      float bia = EBIAS ? bias[col] : 0.0f;
#pragma unroll
      for (int m = 0; m < 4; ++m) {
#pragma unroll
        for (int j = 0; j < 4; ++j) {
          const int line = wr * 64 + m * 16 + r4 + j;
          float xv = acc[m][n][j];
          if (EBIAS)     xv += bia;
          if (ESCALE)    xv *= scale;
          if (EROWSCALE) xv *= rowscale[z * sRS + row0 + line];
          if (EGELU)     xv = 0.5f * xv * (1.0f + erff(xv * 0.70710678118f));
          u16 u;
          if (OUTMODE == 2) { union { u16 s; _Float16 h; } cu; cu.h = (_Float16)xv; u = cu.s; }
          else u = f2bf(xv);
          *(u16*)(sm + ((line * 256 + pc) ^ ((line & 7) << 4))) = u;
        }
      }
    }
    __syncthreads();
    u16* Cb = (u16*)(OUTMODE == 3 ? (sel ? C1 : C0) : C0) + (size_t)z * sC + oc0;
#pragma unroll
    for (int i = 0; i < 8; ++i) {
      const int o = i * 4096 + tid * 16;
      const int line = o >> 8, ps = o & 255;
      f32x4 v = *(const f32x4*)(sm + ((line * 256 + ps) ^ ((line & 7) << 4)));
      *(f32x4*)((char*)(Cb + (size_t)(row0 + line) * ldc) + ps) = v;
    }
  }
}

// f32 -> bf16 convert
__global__ __launch_bounds__(256) void cvt_bf16_k(const float* __restrict__ in, u16* __restrict__ out, int n4) {
  int i = blockIdx.x * blockDim.x + threadIdx.x;
  if (i < n4) {
    float4 v = ((const float4*)in)[i];
    u16x4 o;
    o.x = f2bf(v.x); o.y = f2bf(v.y); o.z = f2bf(v.z); o.w = f2bf(v.w);
    ((u16x4*)out)[i] = o;
  }
}

// batched row softmax over f16 scores -> unnormalized bf16 P + 1/sum
__global__ __launch_bounds__(256) void softmax_k(u16* __restrict__ sc, float* __restrict__ rinv, int rows0) {
  const int widx = blockIdx.x * 4 + (threadIdx.x >> 6);
  const int lane = threadIdx.x & 63;
  u16* row = sc + (size_t)widx * SS;
  const int L = (widx & (SS - 1)) + 1;
  float mx = -1e30f;
  for (int k = 0; k < 4; ++k) {
    const int j0 = k * 512 + lane * 8;
    if (j0 < L) {
      u16x8 v = *(const u16x8*)(row + j0);
      int lim = L - j0; if (lim > 8) lim = 8;
#pragma unroll
      for (int e = 0; e < 8; ++e) {
        if (e < lim) { union { u16 u; _Float16 h; } c; c.u = v[e]; mx = fmaxf(mx, (float)c.h); }
      }
    }
  }
#pragma unroll
  for (int o = 32; o >= 1; o >>= 1) mx = fmaxf(mx, __shfl_xor(mx, o));
  float s = 0.0f;
  for (int k = 0; k < 4; ++k) {
    const int j0 = k * 512 + lane * 8;
    u16x8 v = *(const u16x8*)(row + j0);
    u16x8 w;
#pragma unroll
    for (int e = 0; e < 8; ++e) {
      const int j = j0 + e;
      float ev = 0.0f;
      if (j < L) { union { u16 u; _Float16 h; } c; c.u = v[e]; ev = __expf((float)c.h - mx); s += ev; }
      w[e] = f2bf(ev);
    }
    *(u16x8*)(row + j0) = w;
  }
#pragma unroll
  for (int o = 32; o >= 1; o >>= 1) s += __shfl_xor(s, o);
  if (lane == 0) rinv[rows0 + widx] = 1.0f / s;
}

extern "C" void kernel_launch(void* const* d_in, const int* in_sizes, int n_in,
                              void* d_out, int out_size, void* d_ws, size_t ws_size,
                              hipStream_t stream) {
  const float* x  = (const float*)d_in[0];
  const float* Wq = (const float*)d_in[1];
  const float* bq = (const float*)d_in[2];
  const float* Wk = (const float*)d_in[3];
  const float* bk = (const float*)d_in[4];
  const float* Wv = (const float*)d_in[5];
  const float* bv = (const float*)d_in[6];
  const float* W1 = (const float*)d_in[7];
  const float* b1 = (const float*)d_in[8];
  const float* W2 = (const float*)d_in[9];
  const float* b2 = (const float*)d_in[10];

  char* ws = (char*)d_ws;
  u16*  xb   = (u16*)(ws);                       // 32 MB (later: att)
  u16*  Wcat = (u16*)(ws + 33554432);            // 6 MB: Wq|Wk|Wv rows
  u16*  W1b  = (u16*)(ws + 39845888);
  u16*  W2b  = (u16*)(ws + 48234496);
  u16*  Qb   = (u16*)(ws + 56623104);            // 32 MB
  u16*  Kb   = (u16*)(ws + 90177536);            // 32 MB
  u16*  Vtb  = (u16*)(ws + 123731968);           // 32 MB
  float* rinv = (float*)(ws + 157286400);        // 64 KB
  u16*  big  = (u16*)(ws + 157351936);           // scores/P region; later h
  u16*  att  = xb;

  const size_t base = 157351936ull;
  const size_t avail = ws_size > base ? ws_size - base : 0;
  int GB = 8; while (GB > 1 && (size_t)GB * 8388608ull > avail) GB >>= 1;
  int MC = 16384; while (MC > 2048 && (size_t)MC * 8192ull > avail) MC >>= 1;

  // --- converts (QKV weights into one contiguous [3072 x 1024]) ---
  cvt_bf16_k<<<MTOT * DD / 4 / 256, 256, 0, stream>>>(x, xb, MTOT * DD / 4);
  cvt_bf16_k<<<DD * DD / 4 / 256, 256, 0, stream>>>(Wq, Wcat, DD * DD / 4);
  cvt_bf16_k<<<DD * DD / 4 / 256, 256, 0, stream>>>(Wk, Wcat + DD * DD, DD * DD / 4);
  cvt_bf16_k<<<DD * DD / 4 / 256, 256, 0, stream>>>(Wv, Wcat + 2 * DD * DD, DD * DD / 4);
  cvt_bf16_k<<<DFFN * DD / 4 / 256, 256, 0, stream>>>(W1, W1b, DFFN * DD / 4);
  cvt_bf16_k<<<DFFN * DD / 4 / 256, 256, 0, stream>>>(W2, W2b, DFFN * DD / 4);

  // --- fused QKV projection: N = 3072, grid 24 x 128 ---
  gemm128<1,0,0,0,3,0,0><<<dim3(3 * DD / 128, MTOT / 128), 256, 0, stream>>>(
      xb, Wcat, bq, bk, bv, nullptr, (void*)Qb, (void*)Kb, (void*)Vtb,
      DD, DD, DD, DD, 0.f, 0, 0, 0, 0);

  // --- attention, batched over z in groups of GB ---
  for (int b0 = 0; b0 < NB; b0 += GB) {
    gemm128<0,0,1,0,2,1,0><<<dim3(SS/128, SS/128, GB), 256, 0, stream>>>(
        Qb + (size_t)b0 * SS * DD, Kb + (size_t)b0 * SS * DD,
        nullptr, nullptr, nullptr, nullptr, (void*)big, nullptr, nullptr,
        DD, DD, DD, SS, 0.03125f,
        (long long)SS * DD, (long long)SS * DD, (long long)SS * SS, 0);
    softmax_k<<<GB * SS / 4, 256, 0, stream>>>(big, rinv, b0 * SS);
    gemm128<0,0,0,1,0,0,1><<<dim3(DD/128, SS/128, GB), 256, 0, stream>>>(
        big, Vtb + (size_t)b0 * DD * SS,
        nullptr, nullptr, nullptr, rinv + (size_t)b0 * SS,
        (void*)(att + (size_t)b0 * SS * DD), nullptr, nullptr,
        SS, SS, SS, DD, 0.f,
        (long long)SS * SS, (long long)DD * SS, (long long)SS * DD, SS);
  }

  // --- MLP in chunks of MC rows ---
  for (int c = 0; c < MTOT / MC; ++c) {
    u16* h = big;
    gemm128<1,1,0,0,0,0,0><<<dim3(DFFN/128, MC/128), 256, 0, stream>>>(
        att + (size_t)c * MC * DD, W1b, b1, nullptr, nullptr, nullptr,
        (void*)h, nullptr, nullptr,
        DD, DD, DD, DFFN, 0.f, 0, 0, 0, 0);
    gemm128<1,0,0,0,1,0,0><<<dim3(DD/128, MC/128), 256, 0, stream>>>(
        h, W2b, b2, nullptr, nullptr, nullptr,
        (void*)((float*)d_out + (size_t)c * MC * DD), nullptr, nullptr,
        DFFN, DFFN, DFFN, DD, 0.f, 0, 0, 0, 0);
  }
}

// Round 11
// 724.784 us; speedup vs baseline: 3.9373x; 3.9373x over previous
//
#include <hip/hip_runtime.h>
#include <hip/hip_bf16.h>

#define NB   8
#define SS   2048
#define DD   1024
#define DFFN 4096
#define MTOT (NB*SS)   // 16384

typedef unsigned short u16;
typedef __attribute__((ext_vector_type(4))) float f32x4;
typedef __attribute__((ext_vector_type(8))) short bf16x8;
typedef __attribute__((ext_vector_type(4))) int i32x4;
typedef __attribute__((ext_vector_type(4))) unsigned short u16x4;
typedef __attribute__((ext_vector_type(8))) unsigned short u16x8;

__device__ __forceinline__ u16 f2bf(float f) {
  union { float f; unsigned u; } c; c.f = f;
  unsigned r = c.u + 0x7FFFu + ((c.u >> 16) & 1u);
  return (u16)(r >> 16);
}

__device__ __forceinline__ void gload16(const void* g, void* l) {
  __builtin_amdgcn_global_load_lds(
      (const __attribute__((address_space(1))) void*)(unsigned long long)g,
      (__attribute__((address_space(3))) void*)(unsigned)(unsigned long long)l,
      16, 0, 0);
}

// opaque ds_read_b128 (manual lgkmcnt/vmcnt accounting)
__device__ __forceinline__ bf16x8 dsr128(unsigned addr) {
  i32x4 r;
  asm volatile("ds_read_b128 %0, %1" : "=v"(r) : "v"(addr));
  return __builtin_bit_cast(bf16x8, r);
}

// ---------------------------------------------------------------------------
// R5-proven 128x128 GEMM-BT: 4 waves (2x2), per-wave 64x64, BK=32, 2-buffer
// LDS ring (32KB). __launch_bounds__(256,3): ~124 total regs (64 acc AGPR +
// ~60 VGPR) fits 3-4 waves/SIMD; (256,5) PROVEN BAD (R10: acc spills, 6.8%
// MfmaUtil). Swizzled staging (conflict-free b128), LDS-staged epilogue.
// OUTMODE: 0=bf16, 1=f32, 2=f16, 3=QKV fused (Q,K bf16 rows + V transposed).
// ---------------------------------------------------------------------------
template<int EBIAS, int EGELU, int ESCALE, int EROWSCALE, int OUTMODE, int CSKIP, int CK>
__global__ __launch_bounds__(256, 3)
void gemm128(const u16* __restrict__ A, const u16* __restrict__ B,
             const float* __restrict__ bias0, const float* __restrict__ bias1,
             const float* __restrict__ bias2, const float* __restrict__ rowscale,
             void* __restrict__ C0, void* __restrict__ C1, void* __restrict__ C2,
             int K, int lda, int ldb, int ldc, float scale,
             long long sA, long long sB, long long sC, int sRS)
{
  __shared__ __align__(1024) u16 smem[16384];   // 32 KB

  const int nwg = gridDim.x * gridDim.y;
  const int orig = blockIdx.y * gridDim.x + blockIdx.x;
  const int q = nwg >> 3, r = nwg & 7;
  const int xcd = orig & 7, pos0 = orig >> 3;
  const int wg = (xcd < r ? xcd * (q + 1) : r * (q + 1) + (xcd - r) * q) + pos0;
  const int bx = wg % gridDim.x, by = wg / gridDim.x;
  const int row0 = by * 128, col0 = bx * 128;
  if (CSKIP && col0 > row0 + 127) return;

  const int z = blockIdx.z;
  A += (size_t)z * sA;
  B += (size_t)z * sB;

  int nkt = K >> 5;
  if (CK) { int lim = (row0 + 128) >> 5; if (lim < nkt) nkt = lim; }

  const int tid  = threadIdx.x;
  const int wid  = tid >> 6;
  const int lane = tid & 63;
  const int wr = wid >> 1, wc = wid & 1;

  const int srow = wid * 16 + (lane >> 2);
  const int sunit = (lane & 3) ^ ((lane >> 3) & 3);
  const char* gA = (const char*)A + ((size_t)(row0 + srow) * lda + sunit * 8) * 2;
  const char* gB = (const char*)B + ((size_t)(col0 + srow) * ldb + sunit * 8) * 2;
  const size_t ldab = (size_t)64 * lda * 2;
  const size_t ldbb = (size_t)64 * ldb * 2;

  #define STG(t2) { char* lb = (char*)smem + ((t2) & 1) * 16384; size_t kb = (size_t)(t2) * 64; \
      gload16(gA + kb,        lb + wid * 1024);                                                 \
      gload16(gA + kb + ldab, lb + 4096 + wid * 1024);                                          \
      gload16(gB + kb,        lb + 8192 + wid * 1024);                                          \
      gload16(gB + kb + ldbb, lb + 8192 + 4096 + wid * 1024); }

  const int fr = lane & 15;
  const int ks16 = ((lane >> 4) & 3) * 16;
  const int xm = ((lane >> 1) & 3) << 4;
  const unsigned sbase = (unsigned)(unsigned long long)(void*)smem;

  f32x4 acc[4][4] = {};

  STG(0);
  asm volatile("s_waitcnt vmcnt(0)");
  asm volatile("s_barrier" ::: "memory");

  for (int t = 0; t < nkt; ++t) {
    if (t + 1 < nkt) STG(t + 1);
    const unsigned cb = sbase + (t & 1) * 16384;
    bf16x8 af[4], bf[4];
#pragma unroll
    for (int m = 0; m < 4; ++m)
      af[m] = dsr128(cb + (((wr * 64 + m * 16 + fr) * 64 + ks16) ^ xm));
#pragma unroll
    for (int n = 0; n < 4; ++n)
      bf[n] = dsr128(cb + ((8192 + (wc * 64 + n * 16 + fr) * 64 + ks16) ^ xm));
    asm volatile("s_waitcnt lgkmcnt(0)");
    __builtin_amdgcn_sched_barrier(0);
    __builtin_amdgcn_s_setprio(1);
#pragma unroll
    for (int m = 0; m < 4; ++m)
#pragma unroll
      for (int n = 0; n < 4; ++n)
        acc[m][n] = __builtin_amdgcn_mfma_f32_16x16x32_bf16(af[m], bf[n], acc[m][n], 0, 0, 0);
    __builtin_amdgcn_s_setprio(0);
    asm volatile("s_waitcnt vmcnt(0)");
    asm volatile("s_barrier" ::: "memory");
  }
  #undef STG

  // ---- epilogue via LDS ----
  char* sm = (char*)smem;
  const int r4 = (lane >> 4) * 4;
  const int sel  = (OUTMODE == 3) ? (col0 >> 10) : 0;
  const int oc0  = (OUTMODE == 3) ? (col0 & 1023) : col0;
  const float* bias = (OUTMODE == 3) ? (sel == 0 ? bias0 : sel == 1 ? bias1 : bias2)
                                     : bias0;

  if (OUTMODE == 1) {
#pragma unroll
    for (int p = 0; p < 2; ++p) {
      if (wc == p) {
#pragma unroll
        for (int n = 0; n < 4; ++n) {
          const int col = oc0 + wc * 64 + n * 16 + fr;
          const int pb = (n * 16 + fr) * 4;
          float bia = EBIAS ? bias[col] : 0.0f;
#pragma unroll
          for (int m = 0; m < 4; ++m) {
#pragma unroll
            for (int j = 0; j < 4; ++j) {
              const int line = wr * 64 + m * 16 + r4 + j;
              float xv = acc[m][n][j];
              if (EBIAS)     xv += bia;
              if (ESCALE)    xv *= scale;
              if (EROWSCALE) xv *= rowscale[z * sRS + row0 + line];
              if (EGELU)     xv = 0.5f * xv * (1.0f + erff(xv * 0.70710678118f));
              *(float*)(sm + ((line * 256 + pb) ^ ((line & 7) << 4))) = xv;
            }
          }
        }
      }
      __syncthreads();
      float* Cb = (float*)C0 + (size_t)z * sC;
#pragma unroll
      for (int i = 0; i < 8; ++i) {
        const int o = i * 4096 + tid * 16;
        const int line = o >> 8, ps = o & 255;
        f32x4 v = *(const f32x4*)(sm + ((line * 256 + ps) ^ ((line & 7) << 4)));
        *(f32x4*)((char*)(Cb + (size_t)(row0 + line) * ldc + oc0 + p * 64) + ps) = v;
      }
      __syncthreads();
    }
  } else if (OUTMODE == 3 && sel == 2) {
    // V transposed: line = local col, pos = local row * 2
#pragma unroll
    for (int n = 0; n < 4; ++n) {
      const int line = wc * 64 + n * 16 + fr;
      float bia = EBIAS ? bias[oc0 + line] : 0.0f;
#pragma unroll
      for (int m = 0; m < 4; ++m) {
        const int rb = wr * 64 + m * 16 + r4;
        u16x4 pk;
#pragma unroll
        for (int j = 0; j < 4; ++j) pk[j] = f2bf(acc[m][n][j] + bia);
        *(u16x4*)(sm + ((line * 256 + rb * 2) ^ ((line & 7) << 4))) = pk;
      }
    }
    __syncthreads();
    u16* Cb = (u16*)C2 + (size_t)(row0 >> 11) * (DD * SS) + (row0 & (SS - 1));
#pragma unroll
    for (int i = 0; i < 8; ++i) {
      const int o = i * 4096 + tid * 16;
      const int line = o >> 8, ps = o & 255;
      f32x4 v = *(const f32x4*)(sm + ((line * 256 + ps) ^ ((line & 7) << 4)));
      *(f32x4*)((char*)(Cb + (size_t)(oc0 + line) * SS) + ps) = v;
    }
  } else {
    // 2-byte out (bf16 / f16 / QKV sel<2)
#pragma unroll
    for (int n = 0; n < 4; ++n) {
      const int col = oc0 + wc * 64 + n * 16 + fr;
      const int pc = (wc * 64 + n * 16 + fr) * 2;
      float bia = EBIAS ? bias[col] : 0.0f;
#pragma unroll
      for (int m = 0; m < 4; ++m) {
#pragma unroll
        for (int j = 0; j < 4; ++j) {
          const int line = wr * 64 + m * 16 + r4 + j;
          float xv = acc[m][n][j];
          if (EBIAS)     xv += bia;
          if (ESCALE)    xv *= scale;
          if (EROWSCALE) xv *= rowscale[z * sRS + row0 + line];
          if (EGELU)     xv = 0.5f * xv * (1.0f + erff(xv * 0.70710678118f));
          u16 u;
          if (OUTMODE == 2) { union { u16 s; _Float16 h; } cu; cu.h = (_Float16)xv; u = cu.s; }
          else u = f2bf(xv);
          *(u16*)(sm + ((line * 256 + pc) ^ ((line & 7) << 4))) = u;
        }
      }
    }
    __syncthreads();
    u16* Cb = (u16*)(OUTMODE == 3 ? (sel ? C1 : C0) : C0) + (size_t)z * sC + oc0;
#pragma unroll
    for (int i = 0; i < 8; ++i) {
      const int o = i * 4096 + tid * 16;
      const int line = o >> 8, ps = o & 255;
      f32x4 v = *(const f32x4*)(sm + ((line * 256 + ps) ^ ((line & 7) << 4)));
      *(f32x4*)((char*)(Cb + (size_t)(row0 + line) * ldc) + ps) = v;
    }
  }
}

// f32 -> bf16 convert
__global__ __launch_bounds__(256) void cvt_bf16_k(const float* __restrict__ in, u16* __restrict__ out, int n4) {
  int i = blockIdx.x * blockDim.x + threadIdx.x;
  if (i < n4) {
    float4 v = ((const float4*)in)[i];
    u16x4 o;
    o.x = f2bf(v.x); o.y = f2bf(v.y); o.z = f2bf(v.z); o.w = f2bf(v.w);
    ((u16x4*)out)[i] = o;
  }
}

// batched row softmax over f16 scores -> unnormalized bf16 P + 1/sum
__global__ __launch_bounds__(256) void softmax_k(u16* __restrict__ sc, float* __restrict__ rinv, int rows0) {
  const int widx = blockIdx.x * 4 + (threadIdx.x >> 6);
  const int lane = threadIdx.x & 63;
  u16* row = sc + (size_t)widx * SS;
  const int L = (widx & (SS - 1)) + 1;
  float mx = -1e30f;
  for (int k = 0; k < 4; ++k) {
    const int j0 = k * 512 + lane * 8;
    if (j0 < L) {
      u16x8 v = *(const u16x8*)(row + j0);
      int lim = L - j0; if (lim > 8) lim = 8;
#pragma unroll
      for (int e = 0; e < 8; ++e) {
        if (e < lim) { union { u16 u; _Float16 h; } c; c.u = v[e]; mx = fmaxf(mx, (float)c.h); }
      }
    }
  }
#pragma unroll
  for (int o = 32; o >= 1; o >>= 1) mx = fmaxf(mx, __shfl_xor(mx, o));
  float s = 0.0f;
  for (int k = 0; k < 4; ++k) {
    const int j0 = k * 512 + lane * 8;
    u16x8 v = *(const u16x8*)(row + j0);
    u16x8 w;
#pragma unroll
    for (int e = 0; e < 8; ++e) {
      const int j = j0 + e;
      float ev = 0.0f;
      if (j < L) { union { u16 u; _Float16 h; } c; c.u = v[e]; ev = __expf((float)c.h - mx); s += ev; }
      w[e] = f2bf(ev);
    }
    *(u16x8*)(row + j0) = w;
  }
#pragma unroll
  for (int o = 32; o >= 1; o >>= 1) s += __shfl_xor(s, o);
  if (lane == 0) rinv[rows0 + widx] = 1.0f / s;
}

extern "C" void kernel_launch(void* const* d_in, const int* in_sizes, int n_in,
                              void* d_out, int out_size, void* d_ws, size_t ws_size,
                              hipStream_t stream) {
  const float* x  = (const float*)d_in[0];
  const float* Wq = (const float*)d_in[1];
  const float* bq = (const float*)d_in[2];
  const float* Wk = (const float*)d_in[3];
  const float* bk = (const float*)d_in[4];
  const float* Wv = (const float*)d_in[5];
  const float* bv = (const float*)d_in[6];
  const float* W1 = (const float*)d_in[7];
  const float* b1 = (const float*)d_in[8];
  const float* W2 = (const float*)d_in[9];
  const float* b2 = (const float*)d_in[10];

  char* ws = (char*)d_ws;
  u16*  xb   = (u16*)(ws);                       // 32 MB (later: att)
  u16*  Wcat = (u16*)(ws + 33554432);            // 6 MB: Wq|Wk|Wv rows
  u16*  W1b  = (u16*)(ws + 39845888);
  u16*  W2b  = (u16*)(ws + 48234496);
  u16*  Qb   = (u16*)(ws + 56623104);            // 32 MB
  u16*  Kb   = (u16*)(ws + 90177536);            // 32 MB
  u16*  Vtb  = (u16*)(ws + 123731968);           // 32 MB
  float* rinv = (float*)(ws + 157286400);        // 64 KB
  u16*  big  = (u16*)(ws + 157351936);           // scores/P region; later h
  u16*  att  = xb;

  const size_t base = 157351936ull;
  const size_t avail = ws_size > base ? ws_size - base : 0;
  int GB = 8; while (GB > 1 && (size_t)GB * 8388608ull > avail) GB >>= 1;
  int MC = 16384; while (MC > 2048 && (size_t)MC * 8192ull > avail) MC >>= 1;

  // --- converts (QKV weights into one contiguous [3072 x 1024]) ---
  cvt_bf16_k<<<MTOT * DD / 4 / 256, 256, 0, stream>>>(x, xb, MTOT * DD / 4);
  cvt_bf16_k<<<DD * DD / 4 / 256, 256, 0, stream>>>(Wq, Wcat, DD * DD / 4);
  cvt_bf16_k<<<DD * DD / 4 / 256, 256, 0, stream>>>(Wk, Wcat + DD * DD, DD * DD / 4);
  cvt_bf16_k<<<DD * DD / 4 / 256, 256, 0, stream>>>(Wv, Wcat + 2 * DD * DD, DD * DD / 4);
  cvt_bf16_k<<<DFFN * DD / 4 / 256, 256, 0, stream>>>(W1, W1b, DFFN * DD / 4);
  cvt_bf16_k<<<DFFN * DD / 4 / 256, 256, 0, stream>>>(W2, W2b, DFFN * DD / 4);

  // --- fused QKV projection: N = 3072, grid 24 x 128 ---
  gemm128<1,0,0,0,3,0,0><<<dim3(3 * DD / 128, MTOT / 128), 256, 0, stream>>>(
      xb, Wcat, bq, bk, bv, nullptr, (void*)Qb, (void*)Kb, (void*)Vtb,
      DD, DD, DD, DD, 0.f, 0, 0, 0, 0);

  // --- attention, batched over z in groups of GB ---
  for (int b0 = 0; b0 < NB; b0 += GB) {
    gemm128<0,0,1,0,2,1,0><<<dim3(SS/128, SS/128, GB), 256, 0, stream>>>(
        Qb + (size_t)b0 * SS * DD, Kb + (size_t)b0 * SS * DD,
        nullptr, nullptr, nullptr, nullptr, (void*)big, nullptr, nullptr,
        DD, DD, DD, SS, 0.03125f,
        (long long)SS * DD, (long long)SS * DD, (long long)SS * SS, 0);
    softmax_k<<<GB * SS / 4, 256, 0, stream>>>(big, rinv, b0 * SS);
    gemm128<0,0,0,1,0,0,1><<<dim3(DD/128, SS/128, GB), 256, 0, stream>>>(
        big, Vtb + (size_t)b0 * DD * SS,
        nullptr, nullptr, nullptr, rinv + (size_t)b0 * SS,
        (void*)(att + (size_t)b0 * SS * DD), nullptr, nullptr,
        SS, SS, SS, DD, 0.f,
        (long long)SS * SS, (long long)DD * SS, (long long)SS * DD, SS);
  }

  // --- MLP in chunks of MC rows (MC=16384 when ws allows: fewer grid tails) ---
  for (int c = 0; c < MTOT / MC; ++c) {
    u16* h = big;
    gemm128<1,1,0,0,0,0,0><<<dim3(DFFN/128, MC/128), 256, 0, stream>>>(
        att + (size_t)c * MC * DD, W1b, b1, nullptr, nullptr, nullptr,
        (void*)h, nullptr, nullptr,
        DD, DD, DD, DFFN, 0.f, 0, 0, 0, 0);
    gemm128<1,0,0,0,1,0,0><<<dim3(DD/128, MC/128), 256, 0, stream>>>(
        h, W2b, b2, nullptr, nullptr, nullptr,
        (void*)((float*)d_out + (size_t)c * MC * DD), nullptr, nullptr,
        DFFN, DFFN, DFFN, DD, 0.f, 0, 0, 0, 0);
  }
}

// Round 12
// 702.765 us; speedup vs baseline: 4.0606x; 1.0313x over previous
//
#include <hip/hip_runtime.h>
#include <hip/hip_bf16.h>

#define NB   8
#define SS   2048
#define DD   1024
#define DFFN 4096
#define MTOT (NB*SS)   // 16384

typedef unsigned short u16;
typedef __attribute__((ext_vector_type(4))) float f32x4;
typedef __attribute__((ext_vector_type(8))) short bf16x8;
typedef __attribute__((ext_vector_type(4))) int i32x4;
typedef __attribute__((ext_vector_type(4))) unsigned short u16x4;
typedef __attribute__((ext_vector_type(8))) unsigned short u16x8;

__device__ __forceinline__ u16 f2bf(float f) {
  union { float f; unsigned u; } c; c.f = f;
  unsigned r = c.u + 0x7FFFu + ((c.u >> 16) & 1u);
  return (u16)(r >> 16);
}

__device__ __forceinline__ void gload16(const void* g, void* l) {
  __builtin_amdgcn_global_load_lds(
      (const __attribute__((address_space(1))) void*)(unsigned long long)g,
      (__attribute__((address_space(3))) void*)(unsigned)(unsigned long long)l,
      16, 0, 0);
}

// opaque ds_read_b128 (manual lgkmcnt/vmcnt accounting)
__device__ __forceinline__ bf16x8 dsr128(unsigned addr) {
  i32x4 r;
  asm volatile("ds_read_b128 %0, %1" : "=v"(r) : "v"(addr));
  return __builtin_bit_cast(bf16x8, r);
}

// ---------------------------------------------------------------------------
// R5/R11-proven 128x128 GEMM-BT: 4 waves (2x2), per-wave 64x64, BK=32,
// 2-buffer LDS ring (32KB). Register math: 64 acc (AGPR) + ~60 VGPR = 124.
// MINW=3: safe (R5/R11). MINW=4: budget 128 >= 124 -> 4 blocks/CU (A/B on
// MLP only). MINW=5 PROVEN BAD (R10: budget 102 -> acc spill, 6.8% util).
// OUTMODE: 0=bf16, 1=f32, 2=f16, 3=QKV fused (Q,K bf16 rows + V transposed).
// ---------------------------------------------------------------------------
template<int EBIAS, int EGELU, int ESCALE, int EROWSCALE, int OUTMODE, int CSKIP, int CK, int MINW>
__global__ __launch_bounds__(256, MINW)
void gemm128(const u16* __restrict__ A, const u16* __restrict__ B,
             const float* __restrict__ bias0, const float* __restrict__ bias1,
             const float* __restrict__ bias2, const float* __restrict__ rowscale,
             void* __restrict__ C0, void* __restrict__ C1, void* __restrict__ C2,
             int K, int lda, int ldb, int ldc, float scale,
             long long sA, long long sB, long long sC, int sRS)
{
  __shared__ __align__(1024) u16 smem[16384];   // 32 KB

  const int nwg = gridDim.x * gridDim.y;
  const int orig = blockIdx.y * gridDim.x + blockIdx.x;
  const int q = nwg >> 3, r = nwg & 7;
  const int xcd = orig & 7, pos0 = orig >> 3;
  const int wg = (xcd < r ? xcd * (q + 1) : r * (q + 1) + (xcd - r) * q) + pos0;
  const int bx = wg % gridDim.x, by = wg / gridDim.x;
  const int row0 = by * 128, col0 = bx * 128;
  if (CSKIP && col0 > row0 + 127) return;

  const int z = blockIdx.z;
  A += (size_t)z * sA;
  B += (size_t)z * sB;

  int nkt = K >> 5;
  if (CK) { int lim = (row0 + 128) >> 5; if (lim < nkt) nkt = lim; }

  const int tid  = threadIdx.x;
  const int wid  = tid >> 6;
  const int lane = tid & 63;
  const int wr = wid >> 1, wc = wid & 1;

  const int srow = wid * 16 + (lane >> 2);
  const int sunit = (lane & 3) ^ ((lane >> 3) & 3);
  const char* gA = (const char*)A + ((size_t)(row0 + srow) * lda + sunit * 8) * 2;
  const char* gB = (const char*)B + ((size_t)(col0 + srow) * ldb + sunit * 8) * 2;
  const size_t ldab = (size_t)64 * lda * 2;
  const size_t ldbb = (size_t)64 * ldb * 2;

  #define STG(t2) { char* lb = (char*)smem + ((t2) & 1) * 16384; size_t kb = (size_t)(t2) * 64; \
      gload16(gA + kb,        lb + wid * 1024);                                                 \
      gload16(gA + kb + ldab, lb + 4096 + wid * 1024);                                          \
      gload16(gB + kb,        lb + 8192 + wid * 1024);                                          \
      gload16(gB + kb + ldbb, lb + 8192 + 4096 + wid * 1024); }

  const int fr = lane & 15;
  const int ks16 = ((lane >> 4) & 3) * 16;
  const int xm = ((lane >> 1) & 3) << 4;
  const unsigned sbase = (unsigned)(unsigned long long)(void*)smem;

  f32x4 acc[4][4] = {};

  STG(0);
  asm volatile("s_waitcnt vmcnt(0)");
  asm volatile("s_barrier" ::: "memory");

  for (int t = 0; t < nkt; ++t) {
    if (t + 1 < nkt) STG(t + 1);
    const unsigned cb = sbase + (t & 1) * 16384;
    bf16x8 af[4], bf[4];
#pragma unroll
    for (int m = 0; m < 4; ++m)
      af[m] = dsr128(cb + (((wr * 64 + m * 16 + fr) * 64 + ks16) ^ xm));
#pragma unroll
    for (int n = 0; n < 4; ++n)
      bf[n] = dsr128(cb + ((8192 + (wc * 64 + n * 16 + fr) * 64 + ks16) ^ xm));
    asm volatile("s_waitcnt lgkmcnt(0)");
    __builtin_amdgcn_sched_barrier(0);
    __builtin_amdgcn_s_setprio(1);
#pragma unroll
    for (int m = 0; m < 4; ++m)
#pragma unroll
      for (int n = 0; n < 4; ++n)
        acc[m][n] = __builtin_amdgcn_mfma_f32_16x16x32_bf16(af[m], bf[n], acc[m][n], 0, 0, 0);
    __builtin_amdgcn_s_setprio(0);
    asm volatile("s_waitcnt vmcnt(0)");
    asm volatile("s_barrier" ::: "memory");
  }
  #undef STG

  // ---- epilogue via LDS ----
  char* sm = (char*)smem;
  const int r4 = (lane >> 4) * 4;
  const int sel  = (OUTMODE == 3) ? (col0 >> 10) : 0;
  const int oc0  = (OUTMODE == 3) ? (col0 & 1023) : col0;
  const float* bias = (OUTMODE == 3) ? (sel == 0 ? bias0 : sel == 1 ? bias1 : bias2)
                                     : bias0;

  if (OUTMODE == 1) {
#pragma unroll
    for (int p = 0; p < 2; ++p) {
      if (wc == p) {
#pragma unroll
        for (int n = 0; n < 4; ++n) {
          const int col = oc0 + wc * 64 + n * 16 + fr;
          const int pb = (n * 16 + fr) * 4;
          float bia = EBIAS ? bias[col] : 0.0f;
#pragma unroll
          for (int m = 0; m < 4; ++m) {
#pragma unroll
            for (int j = 0; j < 4; ++j) {
              const int line = wr * 64 + m * 16 + r4 + j;
              float xv = acc[m][n][j];
              if (EBIAS)     xv += bia;
              if (ESCALE)    xv *= scale;
              if (EROWSCALE) xv *= rowscale[z * sRS + row0 + line];
              if (EGELU)     xv = 0.5f * xv * (1.0f + erff(xv * 0.70710678118f));
              *(float*)(sm + ((line * 256 + pb) ^ ((line & 7) << 4))) = xv;
            }
          }
        }
      }
      __syncthreads();
      float* Cb = (float*)C0 + (size_t)z * sC;
#pragma unroll
      for (int i = 0; i < 8; ++i) {
        const int o = i * 4096 + tid * 16;
        const int line = o >> 8, ps = o & 255;
        f32x4 v = *(const f32x4*)(sm + ((line * 256 + ps) ^ ((line & 7) << 4)));
        *(f32x4*)((char*)(Cb + (size_t)(row0 + line) * ldc + oc0 + p * 64) + ps) = v;
      }
      __syncthreads();
    }
  } else if (OUTMODE == 3 && sel == 2) {
    // V transposed: line = local col, pos = local row * 2
#pragma unroll
    for (int n = 0; n < 4; ++n) {
      const int line = wc * 64 + n * 16 + fr;
      float bia = EBIAS ? bias[oc0 + line] : 0.0f;
#pragma unroll
      for (int m = 0; m < 4; ++m) {
        const int rb = wr * 64 + m * 16 + r4;
        u16x4 pk;
#pragma unroll
        for (int j = 0; j < 4; ++j) pk[j] = f2bf(acc[m][n][j] + bia);
        *(u16x4*)(sm + ((line * 256 + rb * 2) ^ ((line & 7) << 4))) = pk;
      }
    }
    __syncthreads();
    u16* Cb = (u16*)C2 + (size_t)(row0 >> 11) * (DD * SS) + (row0 & (SS - 1));
#pragma unroll
    for (int i = 0; i < 8; ++i) {
      const int o = i * 4096 + tid * 16;
      const int line = o >> 8, ps = o & 255;
      f32x4 v = *(const f32x4*)(sm + ((line * 256 + ps) ^ ((line & 7) << 4)));
      *(f32x4*)((char*)(Cb + (size_t)(oc0 + line) * SS) + ps) = v;
    }
  } else {
    // 2-byte out (bf16 / f16 / QKV sel<2)
#pragma unroll
    for (int n = 0; n < 4; ++n) {
      const int col = oc0 + wc * 64 + n * 16 + fr;
      const int pc = (wc * 64 + n * 16 + fr) * 2;
      float bia = EBIAS ? bias[col] : 0.0f;
#pragma unroll
      for (int m = 0; m < 4; ++m) {
#pragma unroll
        for (int j = 0; j < 4; ++j) {
          const int line = wr * 64 + m * 16 + r4 + j;
          float xv = acc[m][n][j];
          if (EBIAS)     xv += bia;
          if (ESCALE)    xv *= scale;
          if (EROWSCALE) xv *= rowscale[z * sRS + row0 + line];
          if (EGELU)     xv = 0.5f * xv * (1.0f + erff(xv * 0.70710678118f));
          u16 u;
          if (OUTMODE == 2) { union { u16 s; _Float16 h; } cu; cu.h = (_Float16)xv; u = cu.s; }
          else u = f2bf(xv);
          *(u16*)(sm + ((line * 256 + pc) ^ ((line & 7) << 4))) = u;
        }
      }
    }
    __syncthreads();
    u16* Cb = (u16*)(OUTMODE == 3 ? (sel ? C1 : C0) : C0) + (size_t)z * sC + oc0;
#pragma unroll
    for (int i = 0; i < 8; ++i) {
      const int o = i * 4096 + tid * 16;
      const int line = o >> 8, ps = o & 255;
      f32x4 v = *(const f32x4*)(sm + ((line * 256 + ps) ^ ((line & 7) << 4)));
      *(f32x4*)((char*)(Cb + (size_t)(row0 + line) * ldc) + ps) = v;
    }
  }
}

// single fused f32->bf16 convert for x|Wq|Wk|Wv|W1|W2 -> contiguous ws region.
// Segment boundaries (in float4 units) are multiples of 256 -> block-uniform.
__global__ __launch_bounds__(256) void cvt_all_k(
    const float* __restrict__ x,  const float* __restrict__ wq,
    const float* __restrict__ wk, const float* __restrict__ wv,
    const float* __restrict__ w1, const float* __restrict__ w2,
    u16* __restrict__ out)
{
  const int i = blockIdx.x * 256 + threadIdx.x;   // float4 index
  const float* src; int off;
  if (i < 4194304)      { src = x;  off = i; }
  else if (i < 4456448) { src = wq; off = i - 4194304; }
  else if (i < 4718592) { src = wk; off = i - 4456448; }
  else if (i < 4980736) { src = wv; off = i - 4718592; }
  else if (i < 6029312) { src = w1; off = i - 4980736; }
  else                  { src = w2; off = i - 6029312; }
  float4 v = ((const float4*)src)[off];
  u16x4 o;
  o.x = f2bf(v.x); o.y = f2bf(v.y); o.z = f2bf(v.z); o.w = f2bf(v.w);
  ((u16x4*)out)[i] = o;
}

// batched row softmax over f16 scores -> unnormalized bf16 P + 1/sum
__global__ __launch_bounds__(256) void softmax_k(u16* __restrict__ sc, float* __restrict__ rinv, int rows0) {
  const int widx = blockIdx.x * 4 + (threadIdx.x >> 6);
  const int lane = threadIdx.x & 63;
  u16* row = sc + (size_t)widx * SS;
  const int L = (widx & (SS - 1)) + 1;
  float mx = -1e30f;
  for (int k = 0; k < 4; ++k) {
    const int j0 = k * 512 + lane * 8;
    if (j0 < L) {
      u16x8 v = *(const u16x8*)(row + j0);
      int lim = L - j0; if (lim > 8) lim = 8;
#pragma unroll
      for (int e = 0; e < 8; ++e) {
        if (e < lim) { union { u16 u; _Float16 h; } c; c.u = v[e]; mx = fmaxf(mx, (float)c.h); }
      }
    }
  }
#pragma unroll
  for (int o = 32; o >= 1; o >>= 1) mx = fmaxf(mx, __shfl_xor(mx, o));
  float s = 0.0f;
  for (int k = 0; k < 4; ++k) {
    const int j0 = k * 512 + lane * 8;
    u16x8 v = *(const u16x8*)(row + j0);
    u16x8 w;
#pragma unroll
    for (int e = 0; e < 8; ++e) {
      const int j = j0 + e;
      float ev = 0.0f;
      if (j < L) { union { u16 u; _Float16 h; } c; c.u = v[e]; ev = __expf((float)c.h - mx); s += ev; }
      w[e] = f2bf(ev);
    }
    *(u16x8*)(row + j0) = w;
  }
#pragma unroll
  for (int o = 32; o >= 1; o >>= 1) s += __shfl_xor(s, o);
  if (lane == 0) rinv[rows0 + widx] = 1.0f / s;
}

extern "C" void kernel_launch(void* const* d_in, const int* in_sizes, int n_in,
                              void* d_out, int out_size, void* d_ws, size_t ws_size,
                              hipStream_t stream) {
  const float* x  = (const float*)d_in[0];
  const float* Wq = (const float*)d_in[1];
  const float* bq = (const float*)d_in[2];
  const float* Wk = (const float*)d_in[3];
  const float* bk = (const float*)d_in[4];
  const float* Wv = (const float*)d_in[5];
  const float* bv = (const float*)d_in[6];
  const float* W1 = (const float*)d_in[7];
  const float* b1 = (const float*)d_in[8];
  const float* W2 = (const float*)d_in[9];
  const float* b2 = (const float*)d_in[10];

  char* ws = (char*)d_ws;
  u16*  xb   = (u16*)(ws);                       // 32 MB (later: att)
  u16*  Wcat = (u16*)(ws + 33554432);            // 6 MB: Wq|Wk|Wv rows
  u16*  W1b  = (u16*)(ws + 39845888);
  u16*  W2b  = (u16*)(ws + 48234496);
  u16*  Qb   = (u16*)(ws + 56623104);            // 32 MB
  u16*  Kb   = (u16*)(ws + 90177536);            // 32 MB
  u16*  Vtb  = (u16*)(ws + 123731968);           // 32 MB
  float* rinv = (float*)(ws + 157286400);        // 64 KB
  u16*  big  = (u16*)(ws + 157351936);           // scores/P region; later h
  u16*  att  = xb;

  const size_t base = 157351936ull;
  const size_t avail = ws_size > base ? ws_size - base : 0;
  int GB = 8; while (GB > 1 && (size_t)GB * 8388608ull > avail) GB >>= 1;
  int MC = 16384; while (MC > 2048 && (size_t)MC * 8192ull > avail) MC >>= 1;

  // --- fused converts: x|Wq|Wk|Wv|W1|W2 -> bf16 in one launch ---
  cvt_all_k<<<27648, 256, 0, stream>>>(x, Wq, Wk, Wv, W1, W2, (u16*)ws);

  // --- fused QKV projection: N = 3072, grid 24 x 128 (MINW=3 control) ---
  gemm128<1,0,0,0,3,0,0,3><<<dim3(3 * DD / 128, MTOT / 128), 256, 0, stream>>>(
      xb, Wcat, bq, bk, bv, nullptr, (void*)Qb, (void*)Kb, (void*)Vtb,
      DD, DD, DD, DD, 0.f, 0, 0, 0, 0);

  // --- attention, batched over z in groups of GB (MINW=3) ---
  for (int b0 = 0; b0 < NB; b0 += GB) {
    gemm128<0,0,1,0,2,1,0,3><<<dim3(SS/128, SS/128, GB), 256, 0, stream>>>(
        Qb + (size_t)b0 * SS * DD, Kb + (size_t)b0 * SS * DD,
        nullptr, nullptr, nullptr, nullptr, (void*)big, nullptr, nullptr,
        DD, DD, DD, SS, 0.03125f,
        (long long)SS * DD, (long long)SS * DD, (long long)SS * SS, 0);
    softmax_k<<<GB * SS / 4, 256, 0, stream>>>(big, rinv, b0 * SS);
    gemm128<0,0,0,1,0,0,1,3><<<dim3(DD/128, SS/128, GB), 256, 0, stream>>>(
        big, Vtb + (size_t)b0 * DD * SS,
        nullptr, nullptr, nullptr, rinv + (size_t)b0 * SS,
        (void*)(att + (size_t)b0 * SS * DD), nullptr, nullptr,
        SS, SS, SS, DD, 0.f,
        (long long)SS * SS, (long long)DD * SS, (long long)SS * DD, SS);
  }

  // --- MLP in chunks of MC rows: MINW=4 (A/B: 4 blocks/CU, 128-reg budget) ---
  for (int c = 0; c < MTOT / MC; ++c) {
    u16* h = big;
    gemm128<1,1,0,0,0,0,0,4><<<dim3(DFFN/128, MC/128), 256, 0, stream>>>(
        att + (size_t)c * MC * DD, W1b, b1, nullptr, nullptr, nullptr,
        (void*)h, nullptr, nullptr,
        DD, DD, DD, DFFN, 0.f, 0, 0, 0, 0);
    gemm128<1,0,0,0,1,0,0,4><<<dim3(DD/128, MC/128), 256, 0, stream>>>(
        h, W2b, b2, nullptr, nullptr, nullptr,
        (void*)((float*)d_out + (size_t)c * MC * DD), nullptr, nullptr,
        DFFN, DFFN, DFFN, DD, 0.f, 0, 0, 0, 0);
  }
}

// Round 13
// 701.576 us; speedup vs baseline: 4.0675x; 1.0017x over previous
//
#include <hip/hip_runtime.h>
#include <hip/hip_bf16.h>

#define NB   8
#define SS   2048
#define DD   1024
#define DFFN 4096
#define MTOT (NB*SS)   // 16384

typedef unsigned short u16;
typedef __attribute__((ext_vector_type(4))) float f32x4;
typedef __attribute__((ext_vector_type(8))) short bf16x8;
typedef __attribute__((ext_vector_type(4))) int i32x4;
typedef __attribute__((ext_vector_type(4))) unsigned short u16x4;
typedef __attribute__((ext_vector_type(8))) unsigned short u16x8;

__device__ __forceinline__ u16 f2bf(float f) {
  union { float f; unsigned u; } c; c.f = f;
  unsigned r = c.u + 0x7FFFu + ((c.u >> 16) & 1u);
  return (u16)(r >> 16);
}

__device__ __forceinline__ void gload16(const void* g, void* l) {
  __builtin_amdgcn_global_load_lds(
      (const __attribute__((address_space(1))) void*)(unsigned long long)g,
      (__attribute__((address_space(3))) void*)(unsigned)(unsigned long long)l,
      16, 0, 0);
}

// opaque ds_read_b128 (manual lgkmcnt/vmcnt accounting)
__device__ __forceinline__ bf16x8 dsr128(unsigned addr) {
  i32x4 r;
  asm volatile("ds_read_b128 %0, %1" : "=v"(r) : "v"(addr));
  return __builtin_bit_cast(bf16x8, r);
}

// ---------------------------------------------------------------------------
// R5/R11-proven 128x128 GEMM-BT: 4 waves (2x2), per-wave 64x64, BK=32,
// 2-buffer LDS ring (32KB). MINW=4 (128-reg budget >= 124 needed; R12 showed
// no spill). MINW=5 PROVEN BAD (R10: acc spill).
// OUTMODE: 0=bf16, 1=f32, 2=f16, 3=QKV fused (Q,K bf16 rows + V transposed).
// ---------------------------------------------------------------------------
template<int EBIAS, int EGELU, int ESCALE, int EROWSCALE, int OUTMODE, int CSKIP, int CK>
__global__ __launch_bounds__(256, 4)
void gemm128(const u16* __restrict__ A, const u16* __restrict__ B,
             const float* __restrict__ bias0, const float* __restrict__ bias1,
             const float* __restrict__ bias2, const float* __restrict__ rowscale,
             void* __restrict__ C0, void* __restrict__ C1, void* __restrict__ C2,
             int K, int lda, int ldb, int ldc, float scale,
             long long sA, long long sB, long long sC, int sRS)
{
  __shared__ __align__(1024) u16 smem[16384];   // 32 KB

  const int nwg = gridDim.x * gridDim.y;
  const int orig = blockIdx.y * gridDim.x + blockIdx.x;
  const int q = nwg >> 3, r = nwg & 7;
  const int xcd = orig & 7, pos0 = orig >> 3;
  const int wg = (xcd < r ? xcd * (q + 1) : r * (q + 1) + (xcd - r) * q) + pos0;
  const int bx = wg % gridDim.x, by = wg / gridDim.x;
  const int row0 = by * 128, col0 = bx * 128;
  if (CSKIP && col0 > row0 + 127) return;

  const int z = blockIdx.z;
  A += (size_t)z * sA;
  B += (size_t)z * sB;

  int nkt = K >> 5;
  if (CK) { int lim = (row0 + 128) >> 5; if (lim < nkt) nkt = lim; }

  const int tid  = threadIdx.x;
  const int wid  = tid >> 6;
  const int lane = tid & 63;
  const int wr = wid >> 1, wc = wid & 1;

  const int srow = wid * 16 + (lane >> 2);
  const int sunit = (lane & 3) ^ ((lane >> 3) & 3);
  const char* gA = (const char*)A + ((size_t)(row0 + srow) * lda + sunit * 8) * 2;
  const char* gB = (const char*)B + ((size_t)(col0 + srow) * ldb + sunit * 8) * 2;
  const size_t ldab = (size_t)64 * lda * 2;
  const size_t ldbb = (size_t)64 * ldb * 2;

  #define STG(t2) { char* lb = (char*)smem + ((t2) & 1) * 16384; size_t kb = (size_t)(t2) * 64; \
      gload16(gA + kb,        lb + wid * 1024);                                                 \
      gload16(gA + kb + ldab, lb + 4096 + wid * 1024);                                          \
      gload16(gB + kb,        lb + 8192 + wid * 1024);                                          \
      gload16(gB + kb + ldbb, lb + 8192 + 4096 + wid * 1024); }

  const int fr = lane & 15;
  const int ks16 = ((lane >> 4) & 3) * 16;
  const int xm = ((lane >> 1) & 3) << 4;
  const unsigned sbase = (unsigned)(unsigned long long)(void*)smem;

  f32x4 acc[4][4] = {};

  STG(0);
  asm volatile("s_waitcnt vmcnt(0)");
  asm volatile("s_barrier" ::: "memory");

  for (int t = 0; t < nkt; ++t) {
    if (t + 1 < nkt) STG(t + 1);
    const unsigned cb = sbase + (t & 1) * 16384;
    bf16x8 af[4], bf[4];
#pragma unroll
    for (int m = 0; m < 4; ++m)
      af[m] = dsr128(cb + (((wr * 64 + m * 16 + fr) * 64 + ks16) ^ xm));
#pragma unroll
    for (int n = 0; n < 4; ++n)
      bf[n] = dsr128(cb + ((8192 + (wc * 64 + n * 16 + fr) * 64 + ks16) ^ xm));
    asm volatile("s_waitcnt lgkmcnt(0)");
    __builtin_amdgcn_sched_barrier(0);
    __builtin_amdgcn_s_setprio(1);
#pragma unroll
    for (int m = 0; m < 4; ++m)
#pragma unroll
      for (int n = 0; n < 4; ++n)
        acc[m][n] = __builtin_amdgcn_mfma_f32_16x16x32_bf16(af[m], bf[n], acc[m][n], 0, 0, 0);
    __builtin_amdgcn_s_setprio(0);
    asm volatile("s_waitcnt vmcnt(0)");
    asm volatile("s_barrier" ::: "memory");
  }
  #undef STG

  // ---- epilogue via LDS ----
  char* sm = (char*)smem;
  const int r4 = (lane >> 4) * 4;
  const int sel  = (OUTMODE == 3) ? (col0 >> 10) : 0;
  const int oc0  = (OUTMODE == 3) ? (col0 & 1023) : col0;
  const float* bias = (OUTMODE == 3) ? (sel == 0 ? bias0 : sel == 1 ? bias1 : bias2)
                                     : bias0;

  if (OUTMODE == 1) {
#pragma unroll
    for (int p = 0; p < 2; ++p) {
      if (wc == p) {
#pragma unroll
        for (int n = 0; n < 4; ++n) {
          const int col = oc0 + wc * 64 + n * 16 + fr;
          const int pb = (n * 16 + fr) * 4;
          float bia = EBIAS ? bias[col] : 0.0f;
#pragma unroll
          for (int m = 0; m < 4; ++m) {
#pragma unroll
            for (int j = 0; j < 4; ++j) {
              const int line = wr * 64 + m * 16 + r4 + j;
              float xv = acc[m][n][j];
              if (EBIAS)     xv += bia;
              if (ESCALE)    xv *= scale;
              if (EROWSCALE) xv *= rowscale[z * sRS + row0 + line];
              if (EGELU)     xv = 0.5f * xv * (1.0f + erff(xv * 0.70710678118f));
              *(float*)(sm + ((line * 256 + pb) ^ ((line & 7) << 4))) = xv;
            }
          }
        }
      }
      __syncthreads();
      float* Cb = (float*)C0 + (size_t)z * sC;
#pragma unroll
      for (int i = 0; i < 8; ++i) {
        const int o = i * 4096 + tid * 16;
        const int line = o >> 8, ps = o & 255;
        f32x4 v = *(const f32x4*)(sm + ((line * 256 + ps) ^ ((line & 7) << 4)));
        *(f32x4*)((char*)(Cb + (size_t)(row0 + line) * ldc + oc0 + p * 64) + ps) = v;
      }
      __syncthreads();
    }
  } else if (OUTMODE == 3 && sel == 2) {
    // V transposed: line = local col, pos = local row * 2
#pragma unroll
    for (int n = 0; n < 4; ++n) {
      const int line = wc * 64 + n * 16 + fr;
      float bia = EBIAS ? bias[oc0 + line] : 0.0f;
#pragma unroll
      for (int m = 0; m < 4; ++m) {
        const int rb = wr * 64 + m * 16 + r4;
        u16x4 pk;
#pragma unroll
        for (int j = 0; j < 4; ++j) pk[j] = f2bf(acc[m][n][j] + bia);
        *(u16x4*)(sm + ((line * 256 + rb * 2) ^ ((line & 7) << 4))) = pk;
      }
    }
    __syncthreads();
    u16* Cb = (u16*)C2 + (size_t)(row0 >> 11) * (DD * SS) + (row0 & (SS - 1));
#pragma unroll
    for (int i = 0; i < 8; ++i) {
      const int o = i * 4096 + tid * 16;
      const int line = o >> 8, ps = o & 255;
      f32x4 v = *(const f32x4*)(sm + ((line * 256 + ps) ^ ((line & 7) << 4)));
      *(f32x4*)((char*)(Cb + (size_t)(oc0 + line) * SS) + ps) = v;
    }
  } else {
    // 2-byte out (bf16 / f16 / QKV sel<2)
#pragma unroll
    for (int n = 0; n < 4; ++n) {
      const int col = oc0 + wc * 64 + n * 16 + fr;
      const int pc = (wc * 64 + n * 16 + fr) * 2;
      float bia = EBIAS ? bias[col] : 0.0f;
#pragma unroll
      for (int m = 0; m < 4; ++m) {
#pragma unroll
        for (int j = 0; j < 4; ++j) {
          const int line = wr * 64 + m * 16 + r4 + j;
          float xv = acc[m][n][j];
          if (EBIAS)     xv += bia;
          if (ESCALE)    xv *= scale;
          if (EROWSCALE) xv *= rowscale[z * sRS + row0 + line];
          if (EGELU)     xv = 0.5f * xv * (1.0f + erff(xv * 0.70710678118f));
          u16 u;
          if (OUTMODE == 2) { union { u16 s; _Float16 h; } cu; cu.h = (_Float16)xv; u = cu.s; }
          else u = f2bf(xv);
          *(u16*)(sm + ((line * 256 + pc) ^ ((line & 7) << 4))) = u;
        }
      }
    }
    __syncthreads();
    u16* Cb = (u16*)(OUTMODE == 3 ? (sel ? C1 : C0) : C0) + (size_t)z * sC + oc0;
#pragma unroll
    for (int i = 0; i < 8; ++i) {
      const int o = i * 4096 + tid * 16;
      const int line = o >> 8, ps = o & 255;
      f32x4 v = *(const f32x4*)(sm + ((line * 256 + ps) ^ ((line & 7) << 4)));
      *(f32x4*)((char*)(Cb + (size_t)(row0 + line) * ldc) + ps) = v;
    }
  }
}

// single fused f32->bf16 convert: x -> out_x (32MB), Wq|Wk|Wv|W1|W2 -> out_w
// (contiguous 22MB). Segment boundaries are multiples of 256 float4 -> uniform.
__global__ __launch_bounds__(256) void cvt_all_k(
    const float* __restrict__ x,  const float* __restrict__ wq,
    const float* __restrict__ wk, const float* __restrict__ wv,
    const float* __restrict__ w1, const float* __restrict__ w2,
    u16* __restrict__ out_x, u16* __restrict__ out_w)
{
  const int i = blockIdx.x * 256 + threadIdx.x;   // float4 index
  const float* src; int off; u16* dst; int dofs;
  if (i < 4194304)      { src = x;  off = i;           dst = out_x; dofs = i; }
  else if (i < 4456448) { src = wq; off = i - 4194304; dst = out_w; dofs = i - 4194304; }
  else if (i < 4718592) { src = wk; off = i - 4456448; dst = out_w; dofs = i - 4194304; }
  else if (i < 4980736) { src = wv; off = i - 4718592; dst = out_w; dofs = i - 4194304; }
  else if (i < 6029312) { src = w1; off = i - 4980736; dst = out_w; dofs = i - 4194304; }
  else                  { src = w2; off = i - 6029312; dst = out_w; dofs = i - 4194304; }
  float4 v = ((const float4*)src)[off];
  u16x4 o;
  o.x = f2bf(v.x); o.y = f2bf(v.y); o.z = f2bf(v.z); o.w = f2bf(v.w);
  ((u16x4*)dst)[dofs] = o;
}

// batched row softmax over f16 scores -> unnormalized bf16 P + 1/sum
__global__ __launch_bounds__(256) void softmax_k(u16* __restrict__ sc, float* __restrict__ rinv, int rows0) {
  const int widx = blockIdx.x * 4 + (threadIdx.x >> 6);
  const int lane = threadIdx.x & 63;
  u16* row = sc + (size_t)widx * SS;
  const int L = (widx & (SS - 1)) + 1;
  float mx = -1e30f;
  for (int k = 0; k < 4; ++k) {
    const int j0 = k * 512 + lane * 8;
    if (j0 < L) {
      u16x8 v = *(const u16x8*)(row + j0);
      int lim = L - j0; if (lim > 8) lim = 8;
#pragma unroll
      for (int e = 0; e < 8; ++e) {
        if (e < lim) { union { u16 u; _Float16 h; } c; c.u = v[e]; mx = fmaxf(mx, (float)c.h); }
      }
    }
  }
#pragma unroll
  for (int o = 32; o >= 1; o >>= 1) mx = fmaxf(mx, __shfl_xor(mx, o));
  float s = 0.0f;
  for (int k = 0; k < 4; ++k) {
    const int j0 = k * 512 + lane * 8;
    u16x8 v = *(const u16x8*)(row + j0);
    u16x8 w;
#pragma unroll
    for (int e = 0; e < 8; ++e) {
      const int j = j0 + e;
      float ev = 0.0f;
      if (j < L) { union { u16 u; _Float16 h; } c; c.u = v[e]; ev = __expf((float)c.h - mx); s += ev; }
      w[e] = f2bf(ev);
    }
    *(u16x8*)(row + j0) = w;
  }
#pragma unroll
  for (int o = 32; o >= 1; o >>= 1) s += __shfl_xor(s, o);
  if (lane == 0) rinv[rows0 + widx] = 1.0f / s;
}

extern "C" void kernel_launch(void* const* d_in, const int* in_sizes, int n_in,
                              void* d_out, int out_size, void* d_ws, size_t ws_size,
                              hipStream_t stream) {
  const float* x  = (const float*)d_in[0];
  const float* Wq = (const float*)d_in[1];
  const float* bq = (const float*)d_in[2];
  const float* Wk = (const float*)d_in[3];
  const float* bk = (const float*)d_in[4];
  const float* Wv = (const float*)d_in[5];
  const float* bv = (const float*)d_in[6];
  const float* W1 = (const float*)d_in[7];
  const float* b1 = (const float*)d_in[8];
  const float* W2 = (const float*)d_in[9];
  const float* b2 = (const float*)d_in[10];

  char* ws = (char*)d_ws;
  // Adaptive packing. GB=8 + MC=16384 needs 190906368 B; GB=4 + MC=8192 needs
  // 157351936 B (safely under the R1-proven ~182.5 MB floor).
  const int big8 = (ws_size >= 190906368ull);
  const int GB = big8 ? 8 : 4;
  const int MC = big8 ? 16384 : 8192;

  u16*  Qb   = (u16*)(ws);                          // 32 MB; att overwrites later
  u16*  Kb   = (u16*)(ws + 33554432);               // 32 MB; h overwrites later
  u16*  Vtb  = (u16*)(ws + 67108864);               // 32 MB
  u16*  big  = (u16*)(ws + 100663296);              // scores/P (8MB*GB); xb first
  const size_t woff = 100663296ull + (size_t)GB * 8388608ull;
  float* rinv = (float*)(ws + woff);                // 64 KB
  u16*  Wcat = (u16*)(ws + woff + 65536);           // 6 MB (Wq|Wk|Wv)
  u16*  W1b  = Wcat + 3 * DD * DD;                  // 8 MB
  u16*  W2b  = W1b + DFFN * DD;                     // 8 MB
  u16*  xb   = big;                                 // x bf16 (32 MB), dead after QKV
  u16*  att  = Qb;                                  // PV out over dead Q rows
  u16*  h    = Kb;                                  // MLP hidden over dead K/Vt

  // --- fused converts: x -> xb, weights -> Wcat|W1b|W2b ---
  cvt_all_k<<<27648, 256, 0, stream>>>(x, Wq, Wk, Wv, W1, W2, xb, Wcat);

  // --- fused QKV projection: N = 3072, grid 24 x 128 ---
  gemm128<1,0,0,0,3,0,0><<<dim3(3 * DD / 128, MTOT / 128), 256, 0, stream>>>(
      xb, Wcat, bq, bk, bv, nullptr, (void*)Qb, (void*)Kb, (void*)Vtb,
      DD, DD, DD, DD, 0.f, 0, 0, 0, 0);

  // --- attention, batched over z in groups of GB ---
  for (int b0 = 0; b0 < NB; b0 += GB) {
    gemm128<0,0,1,0,2,1,0><<<dim3(SS/128, SS/128, GB), 256, 0, stream>>>(
        Qb + (size_t)b0 * SS * DD, Kb + (size_t)b0 * SS * DD,
        nullptr, nullptr, nullptr, nullptr, (void*)big, nullptr, nullptr,
        DD, DD, DD, SS, 0.03125f,
        (long long)SS * DD, (long long)SS * DD, (long long)SS * SS, 0);
    softmax_k<<<GB * SS / 4, 256, 0, stream>>>(big, rinv, b0 * SS);
    gemm128<0,0,0,1,0,0,1><<<dim3(DD/128, SS/128, GB), 256, 0, stream>>>(
        big, Vtb + (size_t)b0 * DD * SS,
        nullptr, nullptr, nullptr, rinv + (size_t)b0 * SS,
        (void*)(att + (size_t)b0 * SS * DD), nullptr, nullptr,
        SS, SS, SS, DD, 0.f,
        (long long)SS * SS, (long long)DD * SS, (long long)SS * DD, SS);
  }

  // --- MLP in chunks of MC rows ---
  for (int c = 0; c < MTOT / MC; ++c) {
    gemm128<1,1,0,0,0,0,0><<<dim3(DFFN/128, MC/128), 256, 0, stream>>>(
        att + (size_t)c * MC * DD, W1b, b1, nullptr, nullptr, nullptr,
        (void*)h, nullptr, nullptr,
        DD, DD, DD, DFFN, 0.f, 0, 0, 0, 0);
    gemm128<1,0,0,0,1,0,0><<<dim3(DD/128, MC/128), 256, 0, stream>>>(
        h, W2b, b2, nullptr, nullptr, nullptr,
        (void*)((float*)d_out + (size_t)c * MC * DD), nullptr, nullptr,
        DFFN, DFFN, DFFN, DD, 0.f, 0, 0, 0, 0);
  }
}